// Round 5
// baseline (40.089 us; speedup 1.0000x reference)
//
#include <hip/hip_runtime.h>

#define NBOX 4096
#define MAXDET 100
#define KSEL 192     // exact top-K target (>= 100 + NMS-suppressed margin)
#define SLICES 4     // producer blocks per image
#define SBOX 1024    // boxes per producer block
#define PNT 256      // producer threads (4 waves)
#define CNT 256      // consumer threads (4 waves)

typedef unsigned long long u64;
typedef unsigned int u32;

__device__ __forceinline__ float iou_xyxy(float4 a, float4 c) {
  float aa = fmaxf(a.z - a.x, 0.f) * fmaxf(a.w - a.y, 0.f);
  float ca = fmaxf(c.z - c.x, 0.f) * fmaxf(c.w - c.y, 0.f);
  float w = fmaxf(fminf(a.z, c.z) - fmaxf(a.x, c.x), 0.f);
  float h = fmaxf(fminf(a.w, c.w) - fmaxf(a.y, c.y), 0.f);
  float inter = w * h;
  return inter / fmaxf(aa + ca - inter, 1e-9f);
}

// One bitonic compare-exchange level over R*64 register-resident u64 keys.
// Element i = r*64+lane. Descending overall when driven by sort/merge below.
template <int R>
__device__ __forceinline__ void merge_step(u64 (&v)[R], int lane, int k, int j) {
  if (j >= 64) {
    int jj = j >> 6;
#pragma unroll
    for (int r = 0; r < R; ++r)
      if (!(r & jj)) {
        int r2 = r | jj;
        bool up = ((r & (k >> 6)) != 0);
        u64 a = v[r], c = v[r2];
        if (up ? (a > c) : (a < c)) { v[r] = c; v[r2] = a; }
      }
  } else {
#pragma unroll
    for (int r = 0; r < R; ++r) {
      u64 a = v[r];
      u64 o = __shfl_xor(a, j);
      bool up = (k >= 64) ? ((r & (k >> 6)) != 0) : ((lane & k) != 0);
      bool is_lower = ((lane & j) == 0);
      bool keep_max = up ^ is_lower;
      v[r] = keep_max ? (a > o ? a : o) : (a < o ? a : o);
    }
  }
}

// Full descending bitonic sort of R*64 register keys (one wave, barrier-free).
template <int R>
__device__ __forceinline__ void sort_regs_desc(u64 (&v)[R], int lane) {
  const int S = R * 64;
  for (int k = 2; k <= S; k <<= 1)
    for (int j = k >> 1; j > 0; j >>= 1) merge_step<R>(v, lane, k, j);
}

// Merge two desc-sorted LDS lists (lenA,lenB <= 256, zero-padded) into
// desc-sorted 512 in regs. Valley sequence (desc++asc) is bitonic; driving
// all levels with k=2S (up=false everywhere) yields descending.
__device__ __forceinline__ void wave_merge512(u64 (&m)[8], const u64* A, int lenA,
                                              const u64* Bp, int lenB, int lane) {
#pragma unroll
  for (int r = 0; r < 4; ++r) {
    int i = r * 64 + lane;
    m[r] = (i < lenA) ? A[i] : 0ull;
  }
#pragma unroll
  for (int r = 0; r < 4; ++r) {
    int i = 255 - (r * 64 + lane);  // reversed (ascending) second half
    m[4 + r] = (i < lenB) ? Bp[i] : 0ull;
  }
  for (int j = 256; j > 0; j >>= 1) merge_step<8>(m, lane, 1024, j);
}

// Chunked greedy NMS over sorted (descending) keys in LDS; boxes gathered
// from `bxp` (global or LDS generic pointer). nslice = blockDim/64.
__device__ void run_nms(const u64* keys, int len, const float4* bxp,
                        float4* chbox, u64* srow, u64* keptkey, float4* keptbox,
                        u64* crossMask, int* p_kept, int tid, int nslice) {
  for (int base = 0; base < len; base += 64) {
    if (*p_kept >= MAXDET) break;  // uniform (written before barrier)
    int L = min(64, len - base);
    if (tid < 64) {  // stage chunk boxes (xyxy)
      if (tid == 0) *crossMask = 0ull;
      float4 bb = make_float4(0.f, 0.f, 0.f, 0.f);
      if (tid < L) {
        u64 k = keys[base + tid];
        int orig = NBOX - 1 - (int)(k & 0xFFFFFFFFull);
        float4 c = bxp[orig];
        bb = make_float4(c.x - 0.5f * c.z, c.y - 0.5f * c.w,
                         c.x + 0.5f * c.z, c.y + 0.5f * c.w);
      }
      chbox[tid] = bb;
      srow[tid] = 0ull;
    }
    __syncthreads();
    int kept0 = *p_kept;
    {  // parallel pair tests: 64 boxes x nslice slices
      int i = tid & 63, slice = tid >> 6;
      if (i < L) {
        float4 a = chbox[i];
        bool hit = false;
        for (int k0 = slice; k0 < kept0 && !hit; k0 += nslice)
          if (iou_xyxy(a, keptbox[k0]) > 0.7f) hit = true;
        if (hit) atomicOr(crossMask, 1ull << i);
        u64 bits = 0ull;
        for (int j = i + 1 + slice; j < L; j += nslice)
          if (iou_xyxy(a, chbox[j]) > 0.7f) bits |= 1ull << j;
        if (bits) atomicOr(&srow[i], bits);
      }
    }
    __syncthreads();
    if (tid < 64) {  // greedy scan: sparse fast path, exact fallback
      u64 removed = *crossMask;
      if (L < 64) removed |= ~((1ull << L) - 1ull);
      u64 K = ~removed;
      u64 myrow = srow[tid];
      u64 contrib = ((K >> tid) & 1ull) ? (myrow & K) : 0ull;
#pragma unroll
      for (int d = 1; d < 64; d <<= 1) contrib |= __shfl_xor(contrib, d);
      u64 keepm;
      if (contrib == 0ull) {
        keepm = K;  // no surviving candidate suppresses another
      } else {
        u64 removed2 = removed;
        keepm = 0ull;
        for (int ii = 0; ii < L; ++ii) {
          u64 row = __shfl(myrow, ii);
          if (!((removed2 >> ii) & 1ull)) {
            keepm |= 1ull << ii;
            removed2 |= row;
          }
        }
      }
      if ((keepm >> tid) & 1ull) {
        int pos = kept0 + __popcll(keepm & ((1ull << tid) - 1ull));
        if (pos < MAXDET) {
          keptkey[pos] = keys[base + tid];
          keptbox[pos] = chbox[tid];
        }
      }
      if (tid == 0) *p_kept = min(MAXDET, kept0 + __popcll(keepm));
    }
    __syncthreads();
  }
}

// ---------------- K1: per-slice exact sorted top-192 ----------------
__global__ __launch_bounds__(PNT) void select_kernel(
    const float* __restrict__ scores, u64* __restrict__ lists,
    int* __restrict__ counts) {
  const int blk = blockIdx.x;
  const int img = blk / SLICES, s = blk % SLICES;
  const int tid = threadIdx.x, wid = tid >> 6, lane = tid & 63;
  __shared__ u64 lA[4][256];
  __shared__ u64 lB[2][256];
  __shared__ int s_cnt;
  if (tid == 0) s_cnt = 0;
  __syncthreads();
  const float* sc = scores + (size_t)img * NBOX + (size_t)s * SBOX;
  u64 v[4];
  int wcnt = 0;
#pragma unroll
  for (int q = 0; q < 4; ++q) {
    int i = wid * 256 + q * 64 + lane;  // [0, 1024)
    float x = sc[i];
    bool valid = (x > 0.5f);
    int ln = s * SBOX + i;              // image-local index
    v[q] = valid ? ((((u64)__float_as_uint(x)) << 32) | (u64)(u32)(NBOX - 1 - ln))
                 : 0ull;
    u64 bal = __ballot(valid);
    if (lane == 0) wcnt += (int)__popcll(bal);
  }
  if (lane == 0) atomicAdd(&s_cnt, wcnt);
  sort_regs_desc<4>(v, lane);  // wave-local 256 keys, barrier-free
#pragma unroll
  for (int r = 0; r < 4; ++r) lA[wid][r * 64 + lane] = v[r];
  __syncthreads();
  if (wid == 0 || wid == 2) {  // round 1: pairwise merge, keep top 256
    u64 m[8];
    wave_merge512(m, lA[wid], 256, lA[wid + 1], 256, lane);
#pragma unroll
    for (int r = 0; r < 4; ++r) lB[wid >> 1][r * 64 + lane] = m[r];
  }
  __syncthreads();
  if (wid == 0) {  // round 2: final merge, write sorted top-192
    u64 m[8];
    wave_merge512(m, lB[0], 256, lB[1], 256, lane);
    u64* dst = lists + ((size_t)img * SLICES + s) * KSEL;
#pragma unroll
    for (int r = 0; r < 3; ++r) dst[r * 64 + lane] = m[r];
  }
  if (tid == 0) counts[img * SLICES + s] = s_cnt;
}

// ---------------- K2: merge lists + NMS + outputs ----------------
__global__ __launch_bounds__(CNT) void nms_kernel(
    const float* __restrict__ boxes, const float* __restrict__ scores,
    const u64* __restrict__ lists, const int* __restrict__ counts,
    float* __restrict__ out, int B) {
  const int img = blockIdx.x;
  const int tid = threadIdx.x, wid = tid >> 6, lane = tid & 63;
  __shared__ u64 lA[SLICES][KSEL];
  __shared__ u64 lB[2][256];
  __shared__ u64 cand[KSEL];
  __shared__ float4 chbox[64];
  __shared__ u64 srow[64];
  __shared__ float4 keptbox[MAXDET];
  __shared__ u64 keptkey[MAXDET];
  __shared__ u64 crossMask;
  __shared__ int s_kept;
  __shared__ u64 skey[NBOX];  // fallback full sort only (32KB)

  const float4* bx = (const float4*)boxes + (size_t)img * NBOX;
  const float* sc = scores + (size_t)img * NBOX;

  const u64* src = lists + (size_t)img * SLICES * KSEL;
  for (int i = tid; i < SLICES * KSEL; i += CNT) ((u64*)lA)[i] = src[i];
  const int M = counts[img * SLICES + 0] + counts[img * SLICES + 1] +
                counts[img * SLICES + 2] + counts[img * SLICES + 3];
  if (tid == 0) s_kept = 0;
  __syncthreads();
  if (wid == 0 || wid == 2) {  // round 1
    u64 m[8];
    wave_merge512(m, lA[wid], KSEL, lA[wid + 1], KSEL, lane);
#pragma unroll
    for (int r = 0; r < 4; ++r) lB[wid >> 1][r * 64 + lane] = m[r];
  }
  __syncthreads();
  if (wid == 0) {  // round 2 -> exact image top-192, sorted desc
    u64 m[8];
    wave_merge512(m, lB[0], 256, lB[1], 256, lane);
#pragma unroll
    for (int r = 0; r < 3; ++r) cand[r * 64 + lane] = m[r];
  }
  __syncthreads();
  const int C = min(M, KSEL);
  run_nms(cand, C, bx, chbox, srow, keptkey, keptbox, &crossMask, &s_kept, tid, CNT / 64);

  // Fully-general fallback (kept<100 with candidates beyond KSEL) — not taken here.
  const bool need_full = (s_kept < MAXDET) && (M > KSEL);
  if (need_full) {
    if (tid == 0) s_kept = 0;
    for (int n = tid; n < NBOX; n += CNT) {
      float x = sc[n];
      u64 key = (u64)(u32)(NBOX - 1 - n);
      if (x > 0.5f) key |= ((u64)__float_as_uint(x)) << 32;
      skey[n] = key;
    }
    __syncthreads();
    for (int k = 2; k <= NBOX; k <<= 1)
      for (int j = k >> 1; j > 0; j >>= 1) {
        for (int t = tid; t < NBOX; t += CNT) {
          int ixj = t ^ j;
          if (ixj > t) {
            u64 a = skey[t], c2 = skey[ixj];
            bool up = (t & k) != 0;
            if (up ? (a > c2) : (a < c2)) { skey[t] = c2; skey[ixj] = a; }
          }
        }
        __syncthreads();
      }
    run_nms(skey, M, bx, chbox, srow, keptkey, keptbox, &crossMask, &s_kept, tid, CNT / 64);
  }

  const int nk = s_kept;
  if (tid < MAXDET) {
    float v0 = 0.f, v1 = 0.f, v2 = 0.f, v3 = 0.f, v4 = 0.f;
    if (tid < nk) {
      u64 key = keptkey[tid];
      int orig = NBOX - 1 - (int)(key & 0xFFFFFFFFull);
      float4 bb = bx[orig];  // original cxcywh
      v0 = bb.x; v1 = bb.y; v2 = bb.z; v3 = bb.w;
      v4 = __uint_as_float((u32)(key >> 32));
    }
    float* o = out + ((size_t)img * MAXDET + tid) * 5;
    o[0] = v0; o[1] = v1; o[2] = v2; o[3] = v3; o[4] = v4;
  }
  if (tid == 0) out[(size_t)B * MAXDET * 5 + img] = (float)nk;
}

// ---------------- Monolithic fallback (only if ws too small) ----------------
#define MNT 1024
#define MNPT 4
__global__ __launch_bounds__(MNT) void postproc_mono(
    const float* __restrict__ boxes, const float* __restrict__ scores,
    float* __restrict__ out, int B) {
  const int b = blockIdx.x;
  const int tid = threadIdx.x, wid = tid >> 6, lane = tid & 63;
  __shared__ u64 skey[NBOX];
  __shared__ float4 chbox[64];
  __shared__ u64 srow[64];
  __shared__ float4 keptbox[MAXDET];
  __shared__ u64 keptkey[MAXDET];
  __shared__ u64 crossMask;
  __shared__ int s_M, s_kept;
  const float* sc = scores + (size_t)b * NBOX;
  const float4* bx = (const float4*)boxes + (size_t)b * NBOX;
  if (tid == 0) { s_M = 0; s_kept = 0; }
  __syncthreads();
  int wcnt = 0;
#pragma unroll
  for (int q = 0; q < MNPT; ++q) {
    int n = tid + q * MNT;
    float x = sc[n];
    bool valid = (x > 0.5f);
    u64 key = (u64)(u32)(NBOX - 1 - n);
    if (valid) key |= ((u64)__float_as_uint(x)) << 32;
    skey[n] = key;
    u64 bal = __ballot(valid);
    if (lane == 0) wcnt += (int)__popcll(bal);
  }
  if (lane == 0) atomicAdd(&s_M, wcnt);
  __syncthreads();
  const int M = s_M;
  for (int k = 2; k <= NBOX; k <<= 1)
    for (int j = k >> 1; j > 0; j >>= 1) {
      for (int t = tid; t < NBOX; t += MNT) {
        int ixj = t ^ j;
        if (ixj > t) {
          u64 a = skey[t], c2 = skey[ixj];
          bool up = (t & k) != 0;
          if (up ? (a > c2) : (a < c2)) { skey[t] = c2; skey[ixj] = a; }
        }
      }
      __syncthreads();
    }
  run_nms(skey, M, bx, chbox, srow, keptkey, keptbox, &crossMask, &s_kept, tid, MNT / 64);
  const int nk = s_kept;
  if (tid < MAXDET) {
    float v0 = 0.f, v1 = 0.f, v2 = 0.f, v3 = 0.f, v4 = 0.f;
    if (tid < nk) {
      u64 key = keptkey[tid];
      int orig = NBOX - 1 - (int)(key & 0xFFFFFFFFull);
      float4 bb = bx[orig];
      v0 = bb.x; v1 = bb.y; v2 = bb.z; v3 = bb.w;
      v4 = __uint_as_float((u32)(key >> 32));
    }
    float* o = out + ((size_t)b * MAXDET + tid) * 5;
    o[0] = v0; o[1] = v1; o[2] = v2; o[3] = v3; o[4] = v4;
  }
  if (tid == 0) out[(size_t)B * MAXDET * 5 + b] = (float)nk;
}

extern "C" void kernel_launch(void* const* d_in, const int* in_sizes, int n_in,
                              void* d_out, int out_size, void* d_ws, size_t ws_size,
                              hipStream_t stream) {
  const float* boxes = (const float*)d_in[0];
  const float* scores = (const float*)d_in[1];
  float* out = (float*)d_out;
  (void)n_in;
  const int B = out_size / (MAXDET * 5 + 1);  // [B,100,5] + [B]
  const size_t lists_bytes = (size_t)B * SLICES * KSEL * sizeof(u64);
  const size_t need = lists_bytes + (size_t)B * SLICES * sizeof(int);
  if (d_ws && ws_size >= need) {
    u64* lists = (u64*)d_ws;
    int* counts = (int*)((char*)d_ws + lists_bytes);
    select_kernel<<<B * SLICES, PNT, 0, stream>>>(scores, lists, counts);
    nms_kernel<<<B, CNT, 0, stream>>>(boxes, scores, lists, counts, out, B);
  } else {
    postproc_mono<<<B, MNT, 0, stream>>>(boxes, scores, out, B);
  }
}

// Round 6
// 37.599 us; speedup vs baseline: 1.0662x; 1.0662x over previous
//
#include <hip/hip_runtime.h>

#define NT 1024
#define NW 16        // waves per block
#define NBOX 4096
#define MAXDET 100
#define KSEL 192     // exact top-K target (>= 100 + NMS-suppressed margin)

typedef unsigned long long u64;
typedef unsigned int u32;

__device__ __forceinline__ float iou_xyxy(float4 a, float4 c) {
  float aa = fmaxf(a.z - a.x, 0.f) * fmaxf(a.w - a.y, 0.f);
  float ca = fmaxf(c.z - c.x, 0.f) * fmaxf(c.w - c.y, 0.f);
  float w = fmaxf(fminf(a.z, c.z) - fmaxf(a.x, c.x), 0.f);
  float h = fmaxf(fminf(a.w, c.w) - fmaxf(a.y, c.y), 0.f);
  float inter = w * h;
  return inter / fmaxf(aa + ca - inter, 1e-9f);
}

// One bitonic compare-exchange level over R*64 register-resident u64 keys.
template <int R>
__device__ __forceinline__ void merge_step(u64 (&v)[R], int lane, int k, int j) {
  if (j >= 64) {
    int jj = j >> 6;
#pragma unroll
    for (int r = 0; r < R; ++r)
      if (!(r & jj)) {
        int r2 = r | jj;
        bool up = ((r & (k >> 6)) != 0);
        u64 a = v[r], c = v[r2];
        if (up ? (a > c) : (a < c)) { v[r] = c; v[r2] = a; }
      }
  } else {
#pragma unroll
    for (int r = 0; r < R; ++r) {
      u64 a = v[r];
      u64 o = __shfl_xor(a, j);
      bool up = (k >= 64) ? ((r & (k >> 6)) != 0) : ((lane & k) != 0);
      bool is_lower = ((lane & j) == 0);
      bool keep_max = up ^ is_lower;
      v[r] = keep_max ? (a > o ? a : o) : (a < o ? a : o);
    }
  }
}

// Full descending bitonic sort of R*64 register keys (one wave, barrier-free).
template <int R>
__device__ __forceinline__ void sort_regs_desc(u64 (&v)[R], int lane) {
  const int S = R * 64;
  for (int k = 2; k <= S; k <<= 1)
    for (int j = k >> 1; j > 0; j >>= 1) merge_step<R>(v, lane, k, j);
}

// Merge two desc-sorted KSEL lists (zero-padded) -> desc top-KSEL into dst.
// Returns count of nonzero (valid) keys among the kept KSEL (uniform in wave).
__device__ __forceinline__ int merge_lists(const u64* A, const u64* Bp,
                                           u64* dst, int lane) {
  u64 m[8];
#pragma unroll
  for (int r = 0; r < 4; ++r) {
    int i = r * 64 + lane;
    m[r] = (i < KSEL) ? A[i] : 0ull;
  }
#pragma unroll
  for (int r = 0; r < 4; ++r) {
    int i = 255 - (r * 64 + lane);  // reversed (ascending) second half
    m[4 + r] = (i < KSEL) ? Bp[i] : 0ull;
  }
  for (int j = 256; j > 0; j >>= 1) merge_step<8>(m, lane, 1024, j);
  int c = (int)__popcll(__ballot(m[0] != 0ull)) +
          (int)__popcll(__ballot(m[1] != 0ull)) +
          (int)__popcll(__ballot(m[2] != 0ull));
#pragma unroll
  for (int r = 0; r < 3; ++r) dst[r * 64 + lane] = m[r];
  return c;
}

// Chunked greedy NMS over sorted (descending) keys in LDS; boxes from global.
__device__ void run_nms(const u64* keys, int len, const float4* __restrict__ bx,
                        float4* chbox, u64* srow, u64* keptkey, float4* keptbox,
                        u64* crossMask, int* p_kept, int tid) {
  for (int base = 0; base < len; base += 64) {
    if (*p_kept >= MAXDET) break;  // uniform (written before a barrier)
    int L = min(64, len - base);
    if (tid < 64) {  // stage chunk boxes (xyxy)
      if (tid == 0) *crossMask = 0ull;
      float4 bb = make_float4(0.f, 0.f, 0.f, 0.f);
      if (tid < L) {
        u64 k = keys[base + tid];
        int orig = NBOX - 1 - (int)(k & 0xFFFFFFFFull);
        float4 c = bx[orig];
        bb = make_float4(c.x - 0.5f * c.z, c.y - 0.5f * c.w,
                         c.x + 0.5f * c.z, c.y + 0.5f * c.w);
      }
      chbox[tid] = bb;
      srow[tid] = 0ull;
    }
    __syncthreads();
    int kept0 = *p_kept;
    {  // parallel pair tests: 64 boxes x NW slices
      int i = tid & 63, slice = tid >> 6;
      if (i < L) {
        float4 a = chbox[i];
        bool hit = false;
        for (int k0 = slice; k0 < kept0 && !hit; k0 += NW)
          if (iou_xyxy(a, keptbox[k0]) > 0.7f) hit = true;
        if (hit) atomicOr(crossMask, 1ull << i);
        u64 bits = 0ull;
        for (int j = i + 1 + slice; j < L; j += NW)
          if (iou_xyxy(a, chbox[j]) > 0.7f) bits |= 1ull << j;
        if (bits) atomicOr(&srow[i], bits);
      }
    }
    __syncthreads();
    if (tid < 64) {  // greedy scan: sparse fast path, exact serial fallback
      u64 removed = *crossMask;
      if (L < 64) removed |= ~((1ull << L) - 1ull);
      u64 K = ~removed;
      u64 myrow = srow[tid];
      u64 contrib = ((K >> tid) & 1ull) ? (myrow & K) : 0ull;
#pragma unroll
      for (int d = 1; d < 64; d <<= 1) contrib |= __shfl_xor(contrib, d);
      u64 keepm;
      if (contrib == 0ull) {
        keepm = K;  // no surviving candidate suppresses another
      } else {
        u64 removed2 = removed;
        keepm = 0ull;
        for (int ii = 0; ii < L; ++ii) {
          u64 row = __shfl(myrow, ii);
          if (!((removed2 >> ii) & 1ull)) {
            keepm |= 1ull << ii;
            removed2 |= row;
          }
        }
      }
      if ((keepm >> tid) & 1ull) {
        int pos = kept0 + __popcll(keepm & ((1ull << tid) - 1ull));
        if (pos < MAXDET) {
          keptkey[pos] = keys[base + tid];
          keptbox[pos] = chbox[tid];
        }
      }
      if (tid == 0) *p_kept = min(MAXDET, kept0 + __popcll(keepm));
    }
    __syncthreads();
  }
}

__global__ __launch_bounds__(NT) void postproc_kernel(
    const float* __restrict__ boxes,   // [B, NBOX, 4] cxcywh
    const float* __restrict__ scores,  // [B, NBOX]
    float* __restrict__ out,           // [B*MAXDET*5] packed, then [B] num
    int B) {
  const int b = blockIdx.x;
  const int tid = threadIdx.x, wid = tid >> 6, lane = tid & 63;

  __shared__ u64 listA[NW][KSEL];   // 24KB (rounds: wave-tops, round-2 out)
  __shared__ u64 listB[8][KSEL];    // 12KB (round-1, round-3 out)
  __shared__ u64 cand[KSEL];        // final sorted top-192
  __shared__ u64 skey[NBOX];        // 32KB, fallback full sort only
  __shared__ float4 chbox[64];
  __shared__ u64 srow[64];
  __shared__ float4 keptbox[MAXDET];
  __shared__ u64 keptkey[MAXDET];
  __shared__ u64 crossMask;
  __shared__ int s_kept, s_C, s_M;

  const float* sc = scores + (size_t)b * NBOX;
  const float4* bx = (const float4*)boxes + (size_t)b * NBOX;

  if (tid == 0) { s_kept = 0; s_M = 0; }

  // ---- Phase 1: load 256 scores/wave, build keys, in-register wave sort ----
  float sreg[4];
  u64 v[4];
#pragma unroll
  for (int q = 0; q < 4; ++q) {
    int i = wid * 256 + q * 64 + lane;
    float x = sc[i];
    sreg[q] = x;
    v[q] = (x > 0.5f)
               ? ((((u64)__float_as_uint(x)) << 32) | (u64)(u32)(NBOX - 1 - i))
               : 0ull;
  }
  sort_regs_desc<4>(v, lane);       // barrier-free, 36 shfl levels
#pragma unroll
  for (int r = 0; r < 3; ++r) listA[wid][r * 64 + lane] = v[r];  // top 192
  __syncthreads();

  // ---- Phase 2: 4-round pairwise merge tree -> exact sorted top-192 ----
  if (wid < 8) merge_lists(listA[2 * wid], listA[2 * wid + 1], listB[wid], lane);
  __syncthreads();
  if (wid < 4) merge_lists(listB[2 * wid], listB[2 * wid + 1], listA[wid], lane);
  __syncthreads();
  if (wid < 2) merge_lists(listA[2 * wid], listA[2 * wid + 1], listB[wid], lane);
  __syncthreads();
  if (wid == 0) {
    int c = merge_lists(listB[0], listB[1], cand, lane);
    if (lane == 0) s_C = c;
  }
  __syncthreads();
  const int C = s_C;  // C < KSEL  =>  cand holds ALL valid boxes

  // ---- Phase 3: chunked NMS (validated structure) ----
  run_nms(cand, C, bx, chbox, srow, keptkey, keptbox, &crossMask, &s_kept, tid);

  // ---- Phase 4: fully-general fallback (kept<100 and candidates dropped) ----
  const bool need_full = (s_kept < MAXDET) && (C == KSEL);
  if (need_full) {
    if (tid == 0) s_kept = 0;
    int wcnt = 0;
#pragma unroll
    for (int q = 0; q < 4; ++q) {
      int i = wid * 256 + q * 64 + lane;
      float x = sreg[q];
      bool valid = (x > 0.5f);
      u64 key = (u64)(u32)(NBOX - 1 - i);
      if (valid) key |= ((u64)__float_as_uint(x)) << 32;
      skey[i] = key;
      u64 bal = __ballot(valid);
      if (lane == 0) wcnt += (int)__popcll(bal);
    }
    if (lane == 0) atomicAdd(&s_M, wcnt);
    __syncthreads();
    const int M = s_M;
    for (int k = 2; k <= NBOX; k <<= 1)
      for (int j = k >> 1; j > 0; j >>= 1) {
        for (int t = tid; t < NBOX; t += NT) {
          int ixj = t ^ j;
          if (ixj > t) {
            u64 a = skey[t], c2 = skey[ixj];
            bool up = (t & k) != 0;
            if (up ? (a > c2) : (a < c2)) { skey[t] = c2; skey[ixj] = a; }
          }
        }
        __syncthreads();
      }
    run_nms(skey, M, bx, chbox, srow, keptkey, keptbox, &crossMask, &s_kept, tid);
  }

  // ---- Phase 5: outputs ----
  const int nk = s_kept;
  if (tid < MAXDET) {
    float v0 = 0.f, v1 = 0.f, v2 = 0.f, v3 = 0.f, v4 = 0.f;
    if (tid < nk) {
      u64 key = keptkey[tid];
      int orig = NBOX - 1 - (int)(key & 0xFFFFFFFFull);
      float4 bb = bx[orig];  // original cxcywh
      v0 = bb.x; v1 = bb.y; v2 = bb.z; v3 = bb.w;
      v4 = __uint_as_float((u32)(key >> 32));
    }
    float* o = out + ((size_t)b * MAXDET + tid) * 5;
    o[0] = v0; o[1] = v1; o[2] = v2; o[3] = v3; o[4] = v4;
  }
  if (tid == 0) out[(size_t)B * MAXDET * 5 + b] = (float)nk;
}

extern "C" void kernel_launch(void* const* d_in, const int* in_sizes, int n_in,
                              void* d_out, int out_size, void* d_ws, size_t ws_size,
                              hipStream_t stream) {
  const float* boxes = (const float*)d_in[0];
  const float* scores = (const float*)d_in[1];
  float* out = (float*)d_out;
  (void)d_ws; (void)ws_size; (void)n_in;
  const int B = out_size / (MAXDET * 5 + 1);  // [B,100,5] + [B]
  postproc_kernel<<<B, NT, 0, stream>>>(boxes, scores, out, B);
}